// Round 3
// baseline (238.036 us; speedup 1.0000x reference)
//
#include <hip/hip_runtime.h>
#include <hip/hip_bf16.h>
#include <stdint.h>

typedef __bf16 bf16x8 __attribute__((ext_vector_type(8)));
typedef float  f32x4  __attribute__((ext_vector_type(4)));

// Weights pre-swizzled into MFMA B-fragment order:
//  slot = (ktile * NF + nfrag); value j of lane l = W[ktile*32 + (l>>4)*8 + j][nfrag*16 + (l&15)]
//  stored at bf16 offset (slot*64 + l)*8 -> one coalesced dwordx4 per fragment.
// Layer 1: K=800 (784 + zero pad), N=512 (500 + pad), 25 k-tiles, 32 n-frags
// Layer 2: K=512 (500 + pad), N=256 (200 + pad), 16 k-tiles, 16 n-frags
// Layer 3: K=256 (200 + pad), N=16 (10 + pad),   8 k-tiles,  1 n-frag

#define KT1 25
#define NF1 32
#define KT2 16
#define NF2 16
#define KT3 8

__global__ void prep_w1(const float* __restrict__ W1, const float* __restrict__ cw,
                        __bf16* __restrict__ w1s) {
  int gid  = blockIdx.x * 256 + threadIdx.x;   // 51200 threads
  int lane = gid & 63;
  int slot = gid >> 6;                         // 0..799
  int t = slot >> 5;
  int f = slot & 31;
  int kbase = t * 32 + ((lane >> 4) << 3);
  int n = f * 16 + (lane & 15);
  float c[9];
#pragma unroll
  for (int i = 0; i < 9; ++i) c[i] = cw[i];
  bf16x8 v;
#pragma unroll
  for (int e = 0; e < 8; ++e) {
    int k = kbase + e;
    float acc = 0.f;
    if (k < 784 && n < 500) {
      int pi = k / 28, pj = k % 28;
#pragma unroll
      for (int dr = 0; dr < 3; ++dr) {
        int r = pi - dr;
        if (r < 0 || r >= 26) continue;
#pragma unroll
        for (int dc = 0; dc < 3; ++dc) {
          int cc = pj - dc;
          if (cc < 0 || cc >= 26) continue;
          acc += c[dr * 3 + dc] * W1[(size_t)(r * 26 + cc) * 500 + n];
        }
      }
    }
    v[e] = (__bf16)acc;
  }
  *(bf16x8*)(w1s + (size_t)(slot * 64 + lane) * 8) = v;
}

__global__ void prep_w2(const float* __restrict__ W2, __bf16* __restrict__ w2s) {
  int gid  = blockIdx.x * 256 + threadIdx.x;   // 16384 threads
  int lane = gid & 63;
  int slot = gid >> 6;
  int t = slot >> 4;
  int f = slot & 15;
  int kbase = t * 32 + ((lane >> 4) << 3);
  int n = f * 16 + (lane & 15);
  bf16x8 v;
#pragma unroll
  for (int e = 0; e < 8; ++e) {
    int k = kbase + e;
    float val = (k < 500 && n < 200) ? W2[(size_t)k * 200 + n] : 0.f;
    v[e] = (__bf16)val;
  }
  *(bf16x8*)(w2s + (size_t)(slot * 64 + lane) * 8) = v;
}

__global__ void prep_w3(const float* __restrict__ W3, __bf16* __restrict__ w3s) {
  int gid  = blockIdx.x * 256 + threadIdx.x;   // 512 threads
  int lane = gid & 63;
  int t    = gid >> 6;
  int kbase = t * 32 + ((lane >> 4) << 3);
  int n = lane & 15;
  bf16x8 v;
#pragma unroll
  for (int e = 0; e < 8; ++e) {
    int k = kbase + e;
    float val = (k < 200 && n < 10) ? W3[(size_t)k * 10 + n] : 0.f;
    v[e] = (__bf16)val;
  }
  *(bf16x8*)(w3s + (size_t)(t * 64 + lane) * 8) = v;
}

// ---- kernel 1: h1 = relu(x @ W1eff + b1), bf16 to global [rows][512] ----
// block = 64 rows x 256 cols (n-half), 4 waves; wave = 4 M-frags x 4 N-frags.
__global__ __launch_bounds__(256, 3) void gemm1(
    const float* __restrict__ x,
    const __bf16* __restrict__ w1s,
    const float* __restrict__ b1,
    __bf16* __restrict__ h1,
    int mtiles)
{
  __shared__ __align__(16) char st[64 * 512];   // 32 KB store-stage
  __shared__ float sb1[256];

  const int tid  = threadIdx.x;
  const int lane = tid & 63;
  const int w    = tid >> 6;
  const int lrow = lane & 15;
  const int lgrp = lane >> 4;
  const int bid  = blockIdx.x;
  const int h    = (bid >= mtiles) ? 1 : 0;     // n-half
  const int mt   = h ? bid - mtiles : bid;
  const int brow = mt * 64;
  const int nc0  = h * 256;

  { int n = nc0 + tid; sb1[tid] = (n < 500) ? b1[n] : 0.f; }

  const f32x4 FZ = {0.f, 0.f, 0.f, 0.f};
  f32x4 acc[4][4];
#pragma unroll
  for (int m = 0; m < 4; ++m)
#pragma unroll
    for (int f = 0; f < 4; ++f) acc[m][f] = FZ;

  // wave's B fragment base: global n-frag = h*16 + w*4 + f
  const bf16x8* wp = (const bf16x8*)w1s + ((size_t)(h * 16 + w * 4) * 64 + lane);
  const float*  xb = x + (size_t)(brow + lrow) * 784;

  f32x4  ar[4][2];
  bf16x8 bfr[4], bnx[4];

  auto load_a = [&](int t) {
    int kb = t * 32 + lgrp * 8;
    if (kb > 776) kb = 776;   // tail clamp; k>=784 rows of w1s are zero
#pragma unroll
    for (int m = 0; m < 4; ++m) {
      const float* p = xb + (size_t)m * 16 * 784 + kb;
      ar[m][0] = *(const f32x4*)p;
      ar[m][1] = *(const f32x4*)(p + 4);
    }
  };

#pragma unroll
  for (int f = 0; f < 4; ++f) bfr[f] = wp[(size_t)f * 64];
  load_a(0);

  for (int t = 0; t < KT1; ++t) {
    bf16x8 afr[4];
#pragma unroll
    for (int m = 0; m < 4; ++m) {
      bf16x8 a;
#pragma unroll
      for (int e = 0; e < 4; ++e) { a[e] = (__bf16)ar[m][0][e]; a[e + 4] = (__bf16)ar[m][1][e]; }
      afr[m] = a;
    }
    if (t < KT1 - 1) load_a(t + 1);
    // prefetch next B tile (t=24 reads one tile past w1s -> w2s region, harmless)
#pragma unroll
    for (int f = 0; f < 4; ++f) bnx[f] = wp[(size_t)((t + 1) * NF1 + f) * 64];

#pragma unroll
    for (int f = 0; f < 4; ++f)
#pragma unroll
      for (int m = 0; m < 4; ++m)
        acc[m][f] = __builtin_amdgcn_mfma_f32_16x16x32_bf16(afr[m], bfr[f], acc[m][f], 0, 0, 0);

#pragma unroll
    for (int f = 0; f < 4; ++f) bfr[f] = bnx[f];
  }

  __syncthreads();  // sb1 ready; st unused before here

  // epilogue: bias + relu + cvt -> LDS (XOR-swizzled), then coalesced copy-out
#pragma unroll
  for (int m = 0; m < 4; ++m) {
#pragma unroll
    for (int f = 0; f < 4; ++f) {
      int col = w * 64 + f * 16 + lrow;       // 0..255 within half
      float bias = sb1[col];
#pragma unroll
      for (int r = 0; r < 4; ++r) {
        int row = m * 16 + lgrp * 4 + r;
        float v = fmaxf(acc[m][f][r] + bias, 0.f);
        int off = row * 512 + ((col * 2) ^ ((row & 7) << 4));
        *(__bf16*)(st + off) = (__bf16)v;
      }
    }
  }
  __syncthreads();

  __bf16* orow = h1 + (size_t)brow * 512 + nc0;
#pragma unroll
  for (int i = 0; i < 8; ++i) {
    int c   = i * 256 + tid;    // 16B-chunk id, 0..2047
    int row = c >> 5;           // 32 chunks per row-half
    int ci  = c & 31;
    f32x4 vv = *(const f32x4*)(st + row * 512 + ((ci * 16) ^ ((row & 7) << 4)));
    *(f32x4*)((char*)(orow + (size_t)row * 512) + ci * 16) = vv;
  }
}

// ---- kernel 2: layers 2+3 fused. block = 64 rows, 4 waves ----
__global__ __launch_bounds__(256, 3) void gemm23(
    const __bf16* __restrict__ h1,
    const __bf16* __restrict__ w2s, const __bf16* __restrict__ w3s,
    const float* __restrict__ b2, const float* __restrict__ b3,
    float* __restrict__ out)
{
  __shared__ __align__(16) char h2s[64 * 512];   // 32 KB
  __shared__ float sb2[256];

  const int tid  = threadIdx.x;
  const int lane = tid & 63;
  const int w    = tid >> 6;
  const int lrow = lane & 15;
  const int lgrp = lane >> 4;
  const int brow = blockIdx.x * 64;

  sb2[tid] = (tid < 200) ? b2[tid] : 0.f;

  const f32x4 FZ = {0.f, 0.f, 0.f, 0.f};
  f32x4 acc[4][4];
#pragma unroll
  for (int m = 0; m < 4; ++m)
#pragma unroll
    for (int f = 0; f < 4; ++f) acc[m][f] = FZ;

  const bf16x8* wp = (const bf16x8*)w2s + ((size_t)(w * 4) * 64 + lane);
  const __bf16* hb = h1 + (size_t)(brow + lrow) * 512;

  bf16x8 ar[4], an[4], bfr[4], bnx[4];

#pragma unroll
  for (int m = 0; m < 4; ++m)
    ar[m] = *(const bf16x8*)(hb + (size_t)m * 16 * 512 + lgrp * 8);
#pragma unroll
  for (int f = 0; f < 4; ++f) bfr[f] = wp[(size_t)f * 64];

  for (int t = 0; t < KT2; ++t) {
    if (t < KT2 - 1) {
#pragma unroll
      for (int m = 0; m < 4; ++m)
        an[m] = *(const bf16x8*)(hb + (size_t)m * 16 * 512 + (t + 1) * 32 + lgrp * 8);
    }
    // prefetch next B (t=15 reads one tile past w2s -> w3s region, harmless)
#pragma unroll
    for (int f = 0; f < 4; ++f) bnx[f] = wp[(size_t)((t + 1) * NF2 + f) * 64];

#pragma unroll
    for (int f = 0; f < 4; ++f)
#pragma unroll
      for (int m = 0; m < 4; ++m)
        acc[m][f] = __builtin_amdgcn_mfma_f32_16x16x32_bf16(ar[m], bfr[f], acc[m][f], 0, 0, 0);

#pragma unroll
    for (int m = 0; m < 4; ++m) ar[m] = an[m];
#pragma unroll
    for (int f = 0; f < 4; ++f) bfr[f] = bnx[f];
  }

  __syncthreads();  // sb2 ready

  // epilogue -> h2s (cols >= 200 exact zeros: acc==0, bias==0)
#pragma unroll
  for (int m = 0; m < 4; ++m) {
#pragma unroll
    for (int f = 0; f < 4; ++f) {
      int col = w * 64 + f * 16 + lrow;
      float bias = sb2[col];
#pragma unroll
      for (int r = 0; r < 4; ++r) {
        int row = m * 16 + lgrp * 4 + r;
        float v = fmaxf(acc[m][f][r] + bias, 0.f);
        int off = row * 512 + ((col * 2) ^ ((row & 7) << 4));
        *(__bf16*)(h2s + off) = (__bf16)v;
      }
    }
  }
  __syncthreads();

  // layer 3: wave w owns rows w*16..w*16+15
  {
    f32x4 a3 = FZ;
    const bf16x8* w3p = (const bf16x8*)w3s + lane;
#pragma unroll
    for (int t = 0; t < KT3; ++t) {
      int row = w * 16 + lrow;
      int off = row * 512 + ((t * 64 + lgrp * 16) ^ ((row & 7) << 4));
      bf16x8 a = *(const bf16x8*)(h2s + off);
      a3 = __builtin_amdgcn_mfma_f32_16x16x32_bf16(a, w3p[(size_t)t * 64], a3, 0, 0, 0);
    }
    if (lrow < 10) {
      float bias = b3[lrow];
#pragma unroll
      for (int r = 0; r < 4; ++r)
        out[(size_t)(brow + w * 16 + lgrp * 4 + r) * 10 + lrow] = a3[r] + bias;
    }
  }
}

extern "C" void kernel_launch(void* const* d_in, const int* in_sizes, int n_in,
                              void* d_out, int out_size, void* d_ws, size_t ws_size,
                              hipStream_t stream) {
  const float* x  = (const float*)d_in[0];
  const float* cw = (const float*)d_in[1];
  const float* W1 = (const float*)d_in[2];
  const float* b1 = (const float*)d_in[3];
  const float* W2 = (const float*)d_in[4];
  const float* b2 = (const float*)d_in[5];
  const float* W3 = (const float*)d_in[6];
  const float* b3 = (const float*)d_in[7];
  float* out = (float*)d_out;

  __bf16* w1s = (__bf16*)d_ws;                      // 409600 bf16 (800 KB)
  __bf16* w2s = w1s + (size_t)KT1 * NF1 * 64 * 8;   // 131072 bf16 (256 KB)
  __bf16* w3s = w2s + (size_t)KT2 * NF2 * 64 * 8;   // 4096 bf16 (8 KB)

  size_t woff  = ((size_t)KT1 * NF1 + KT2 * NF2 + KT3) * 64 * 8 * sizeof(__bf16);
  size_t h1off = (woff + 255) & ~(size_t)255;
  __bf16* h1   = (__bf16*)((char*)d_ws + h1off);

  // chunk batch so h1 fits in remaining workspace (1024 B per row)
  size_t avail   = (ws_size > h1off) ? ws_size - h1off : 0;
  size_t maxrows = avail / 1024;
  int chunk = 65536;
  while ((size_t)chunk > maxrows && chunk > 64) chunk >>= 1;

  prep_w1<<<200, 256, 0, stream>>>(W1, cw, w1s);
  prep_w2<<<64, 256, 0, stream>>>(W2, w2s);
  prep_w3<<<2, 256, 0, stream>>>(W3, w3s);

  for (int r0 = 0; r0 < 65536; r0 += chunk) {
    int mt = chunk / 64;
    gemm1<<<mt * 2, 256, 0, stream>>>(x + (size_t)r0 * 784, w1s, b1, h1, mt);
    gemm23<<<mt, 256, 0, stream>>>(h1, w2s, w3s, b2, b3, out + (size_t)r0 * 10);
  }
}

// Round 4
// 102.648 us; speedup vs baseline: 2.3190x; 2.3190x over previous
//
#include <hip/hip_runtime.h>
#include <hip/hip_bf16.h>
#include <stdint.h>

typedef __bf16 bf16x8 __attribute__((ext_vector_type(8)));
typedef float  f32x4  __attribute__((ext_vector_type(4)));

// Weights pre-swizzled into MFMA B-fragment order:
//  slot = (ktile * NF + nfrag); value j of lane l = W[ktile*32 + (l>>4)*8 + j][nfrag*16 + (l&15)]
//  stored at bf16 offset (slot*64 + l)*8 -> one coalesced dwordx4 per fragment.
// Layer 1: K=800 (784 + zero pad), N=512 (500 + pad), 25 k-tiles, 32 n-frags
// Layer 2: K=512 (500 + pad), N=256 (200 + pad), 16 k-tiles, 16 n-frags
// Layer 3: K=256 (200 + pad), N=16 (10 + pad),   8 k-tiles,  1 n-frag

#define KT1 25
#define NF1 32
#define KT2 16
#define NF2 16
#define KT3 8

__global__ void prep_w1(const float* __restrict__ W1, const float* __restrict__ cw,
                        __bf16* __restrict__ w1s) {
  int gid  = blockIdx.x * 256 + threadIdx.x;   // 51200 threads
  int lane = gid & 63;
  int slot = gid >> 6;                         // 0..799
  int t = slot >> 5;
  int f = slot & 31;
  int kbase = t * 32 + ((lane >> 4) << 3);
  int n = f * 16 + (lane & 15);
  float c[9];
#pragma unroll
  for (int i = 0; i < 9; ++i) c[i] = cw[i];
  bf16x8 v;
#pragma unroll
  for (int e = 0; e < 8; ++e) {
    int k = kbase + e;
    float acc = 0.f;
    if (k < 784 && n < 500) {
      int pi = k / 28, pj = k % 28;
#pragma unroll
      for (int dr = 0; dr < 3; ++dr) {
        int r = pi - dr;
        if (r < 0 || r >= 26) continue;
#pragma unroll
        for (int dc = 0; dc < 3; ++dc) {
          int cc = pj - dc;
          if (cc < 0 || cc >= 26) continue;
          acc += c[dr * 3 + dc] * W1[(size_t)(r * 26 + cc) * 500 + n];
        }
      }
    }
    v[e] = (__bf16)acc;
  }
  *(bf16x8*)(w1s + (size_t)(slot * 64 + lane) * 8) = v;
}

__global__ void prep_w2(const float* __restrict__ W2, __bf16* __restrict__ w2s) {
  int gid  = blockIdx.x * 256 + threadIdx.x;   // 16384 threads
  int lane = gid & 63;
  int slot = gid >> 6;
  int t = slot >> 4;
  int f = slot & 15;
  int kbase = t * 32 + ((lane >> 4) << 3);
  int n = f * 16 + (lane & 15);
  bf16x8 v;
#pragma unroll
  for (int e = 0; e < 8; ++e) {
    int k = kbase + e;
    float val = (k < 500 && n < 200) ? W2[(size_t)k * 200 + n] : 0.f;
    v[e] = (__bf16)val;
  }
  *(bf16x8*)(w2s + (size_t)(slot * 64 + lane) * 8) = v;
}

__global__ void prep_w3(const float* __restrict__ W3, __bf16* __restrict__ w3s) {
  int gid  = blockIdx.x * 256 + threadIdx.x;   // 512 threads
  int lane = gid & 63;
  int t    = gid >> 6;
  int kbase = t * 32 + ((lane >> 4) << 3);
  int n = lane & 15;
  bf16x8 v;
#pragma unroll
  for (int e = 0; e < 8; ++e) {
    int k = kbase + e;
    float val = (k < 200 && n < 10) ? W3[(size_t)k * 10 + n] : 0.f;
    v[e] = (__bf16)val;
  }
  *(bf16x8*)(w3s + (size_t)(t * 64 + lane) * 8) = v;
}

// ---- fused 3-layer MLP, 64 rows/block, 4 waves, A staged via global_load_lds ----
// xs physical layout: chunk (r,q) at byte r*128 + q*16 holds x[brow+r][t*32 + (q^(r&7))*4 ..+4)
// (pre-swizzled source; swizzled ds_read -> conflict-free per G4/rule21)
__global__ __launch_bounds__(256, 2) void mlp_fused(
    const float* __restrict__ x,
    const __bf16* __restrict__ w1s, const __bf16* __restrict__ w2s,
    const __bf16* __restrict__ w3s,
    const float* __restrict__ b1, const float* __restrict__ b2,
    const float* __restrict__ b3,
    float* __restrict__ out)
{
  __shared__ __align__(16) char xs[64 * 128];    // 8 KB x-tile stage
  __shared__ __align__(16) char h1[64 * 1024];   // 64 KB h1 (bf16, swizzled)
  __shared__ float sb1[512];
  __shared__ float sb2[256];

  const int tid  = threadIdx.x;
  const int lane = tid & 63;
  const int w    = tid >> 6;   // wave 0..3
  const int lrow = lane & 15;
  const int lgrp = lane >> 4;  // 0..3
  const int brow = blockIdx.x * 64;

  sb1[tid]       = (tid < 500) ? b1[tid] : 0.f;
  sb1[tid + 256] = (tid + 256 < 500) ? b1[tid + 256] : 0.f;
  sb2[tid]       = (tid < 200) ? b2[tid] : 0.f;

  const f32x4 FZ = {0.f, 0.f, 0.f, 0.f};

  // ---------------- Layer 1: h1 = relu(x @ W1eff + b1) ----------------
  f32x4 acc1[4][8];
#pragma unroll
  for (int m = 0; m < 4; ++m)
#pragma unroll
    for (int f = 0; f < 8; ++f) acc1[m][f] = FZ;

  const bf16x8* w1p = (const bf16x8*)w1s + ((size_t)(w * 8) * 64 + lane);

  // cooperative stage of one 64x32 fp32 x-tile (8 KB): 2 global_load_lds x16B per wave
  auto stage = [&](int t) {
#pragma unroll
    for (int i = 0; i < 2; ++i) {
      int c = i * 256 + tid;          // chunk 0..511
      int r = c >> 3, q = c & 7;
      int gk = t * 32 + ((q ^ (r & 7)) << 2);
      if (gk > 780) gk = 768;         // tail clamp: garbage hits zero B rows (k>=784)
      const float* gsrc = x + (size_t)(brow + r) * 784 + gk;
      __builtin_amdgcn_global_load_lds(
          (const __attribute__((address_space(1))) void*)gsrc,
          (__attribute__((address_space(3))) void*)(xs + (size_t)(i * 256 + w * 64) * 16),
          16, 0, 0);
    }
  };

  bf16x8 bfr[8];
  stage(0);
#pragma unroll
  for (int f = 0; f < 8; ++f) bfr[f] = w1p[(size_t)f * 64];
  __syncthreads();   // drains stage(0); sb1/sb2 ready

  for (int t = 0; t < KT1; ++t) {
    // A fragments from staged LDS (swizzled read, 2-way conflicts = free)
    f32x4 u[4][2];
#pragma unroll
    for (int m = 0; m < 4; ++m) {
      int r  = m * 16 + lrow;
      int sw = (r & 7) << 4;
      int b  = r * 128 + ((lgrp * 32) ^ sw);
      int b2_ = r * 128 + ((lgrp * 32 + 16) ^ sw);
      u[m][0] = *(const f32x4*)(xs + b);
      u[m][1] = *(const f32x4*)(xs + b2_);
    }
    bf16x8 afr[4];
#pragma unroll
    for (int m = 0; m < 4; ++m) {
      bf16x8 a;
#pragma unroll
      for (int e = 0; e < 4; ++e) { a[e] = (__bf16)u[m][0][e]; a[e + 4] = (__bf16)u[m][1][e]; }
      afr[m] = a;
    }

    // first half MFMA (B frags 0..3, loaded last iteration)
#pragma unroll
    for (int f = 0; f < 4; ++f)
#pragma unroll
      for (int m = 0; m < 4; ++m)
        acc1[m][f] = __builtin_amdgcn_mfma_f32_16x16x32_bf16(afr[m], bfr[f], acc1[m][f], 0, 0, 0);

    __syncthreads();                 // all waves done reading xs(t)
    if (t + 1 < KT1) stage(t + 1);   // overwrite xs; latency hidden by MFMAs below
#pragma unroll
    for (int f = 0; f < 4; ++f)      // refill B frags 0..3 for t+1 (t=24 overruns into w2s: harmless)
      bfr[f] = w1p[(size_t)((t + 1) * NF1 + f) * 64];

    // second half MFMA (B frags 4..7) — covers stage + B-load latency
#pragma unroll
    for (int f = 4; f < 8; ++f)
#pragma unroll
      for (int m = 0; m < 4; ++m)
        acc1[m][f] = __builtin_amdgcn_mfma_f32_16x16x32_bf16(afr[m], bfr[f], acc1[m][f], 0, 0, 0);
#pragma unroll
    for (int f = 4; f < 8; ++f)
      bfr[f] = w1p[(size_t)((t + 1) * NF1 + f) * 64];

    __syncthreads();                 // stage(t+1) drained (compiler vmcnt(0) before barrier)
  }

  // epilogue 1: bias + relu + cvt -> h1 (XOR-swizzled rows)
#pragma unroll
  for (int m = 0; m < 4; ++m) {
#pragma unroll
    for (int f = 0; f < 8; ++f) {
      int col = w * 128 + f * 16 + lrow;
      float bias = sb1[col];
#pragma unroll
      for (int r = 0; r < 4; ++r) {
        int row = m * 16 + lgrp * 4 + r;
        float v = fmaxf(acc1[m][f][r] + bias, 0.f);
        int off = row * 1024 + ((col * 2) ^ ((row & 7) << 4));
        *(__bf16*)(h1 + off) = (__bf16)v;
      }
    }
  }
  __syncthreads();

  // ---------------- Layer 2: h2 = relu(h1 @ W2 + b2) ----------------
  f32x4 acc2[4][4];
#pragma unroll
  for (int m = 0; m < 4; ++m)
#pragma unroll
    for (int f = 0; f < 4; ++f) acc2[m][f] = FZ;

  const bf16x8* w2p = (const bf16x8*)w2s + ((size_t)(w * 4) * 64 + lane);

  bf16x8 b2a[4], b2b[4];
#pragma unroll
  for (int f = 0; f < 4; ++f) b2a[f] = w2p[(size_t)f * 64];

  for (int t = 0; t < KT2; t += 2) {
#pragma unroll
    for (int f = 0; f < 4; ++f) b2b[f] = w2p[(size_t)((t + 1) * NF2 + f) * 64];
    {
      bf16x8 a2[4];
#pragma unroll
      for (int m = 0; m < 4; ++m) {
        int row = m * 16 + lrow;
        int off = row * 1024 + ((t * 64 + lgrp * 16) ^ ((row & 7) << 4));
        a2[m] = *(const bf16x8*)(h1 + off);
      }
#pragma unroll
      for (int f = 0; f < 4; ++f)
#pragma unroll
        for (int m = 0; m < 4; ++m)
          acc2[m][f] = __builtin_amdgcn_mfma_f32_16x16x32_bf16(a2[m], b2a[f], acc2[m][f], 0, 0, 0);
    }
#pragma unroll
    for (int f = 0; f < 4; ++f) b2a[f] = w2p[(size_t)((t + 2) * NF2 + f) * 64];
    {
      bf16x8 a2[4];
#pragma unroll
      for (int m = 0; m < 4; ++m) {
        int row = m * 16 + lrow;
        int off = row * 1024 + (((t + 1) * 64 + lgrp * 16) ^ ((row & 7) << 4));
        a2[m] = *(const bf16x8*)(h1 + off);
      }
#pragma unroll
      for (int f = 0; f < 4; ++f)
#pragma unroll
        for (int m = 0; m < 4; ++m)
          acc2[m][f] = __builtin_amdgcn_mfma_f32_16x16x32_bf16(a2[m], b2b[f], acc2[m][f], 0, 0, 0);
    }
  }

  __syncthreads();   // all h1 reads done before overwriting with h2

  // epilogue 2 -> h2 in reused LDS (cols >= 200 exact zeros: acc==0, bias==0)
#pragma unroll
  for (int m = 0; m < 4; ++m) {
#pragma unroll
    for (int f = 0; f < 4; ++f) {
      int col = w * 64 + f * 16 + lrow;
      float bias = sb2[col];
#pragma unroll
      for (int r = 0; r < 4; ++r) {
        int row = m * 16 + lgrp * 4 + r;
        float v = fmaxf(acc2[m][f][r] + bias, 0.f);
        int off = row * 512 + ((col * 2) ^ ((row & 7) << 4));
        *(__bf16*)(h1 + off) = (__bf16)v;
      }
    }
  }
  __syncthreads();

  // ---------------- Layer 3: out = h2 @ W3 + b3 (wave w owns rows w*16..) ----------------
  {
    f32x4 a3 = FZ;
    const bf16x8* w3p = (const bf16x8*)w3s + lane;
#pragma unroll
    for (int t = 0; t < KT3; ++t) {
      int row = w * 16 + lrow;
      int off = row * 512 + ((t * 64 + lgrp * 16) ^ ((row & 7) << 4));
      bf16x8 a = *(const bf16x8*)(h1 + off);
      a3 = __builtin_amdgcn_mfma_f32_16x16x32_bf16(a, w3p[(size_t)t * 64], a3, 0, 0, 0);
    }
    if (lrow < 10) {
      float bias = b3[lrow];
#pragma unroll
      for (int r = 0; r < 4; ++r)
        out[(size_t)(brow + w * 16 + lgrp * 4 + r) * 10 + lrow] = a3[r] + bias;
    }
  }
}

extern "C" void kernel_launch(void* const* d_in, const int* in_sizes, int n_in,
                              void* d_out, int out_size, void* d_ws, size_t ws_size,
                              hipStream_t stream) {
  const float* x  = (const float*)d_in[0];
  const float* cw = (const float*)d_in[1];
  const float* W1 = (const float*)d_in[2];
  const float* b1 = (const float*)d_in[3];
  const float* W2 = (const float*)d_in[4];
  const float* b2 = (const float*)d_in[5];
  const float* W3 = (const float*)d_in[6];
  const float* b3 = (const float*)d_in[7];
  float* out = (float*)d_out;

  __bf16* w1s = (__bf16*)d_ws;                      // 800 KB
  __bf16* w2s = w1s + (size_t)KT1 * NF1 * 64 * 8;   // 256 KB
  __bf16* w3s = w2s + (size_t)KT2 * NF2 * 64 * 8;   // 8 KB

  prep_w1<<<200, 256, 0, stream>>>(W1, cw, w1s);
  prep_w2<<<64, 256, 0, stream>>>(W2, w2s);
  prep_w3<<<2, 256, 0, stream>>>(W3, w3s);

  mlp_fused<<<65536 / 64, 256, 0, stream>>>(x, w1s, w2s, w3s, b1, b2, b3, out);
}